// Round 9
// baseline (254.421 us; speedup 1.0000x reference)
//
#include <hip/hip_runtime.h>
#include <hip/hip_bf16.h>

// Problem constants (match reference setup_inputs)
#define N_CONV   4
#define C_IN     64
#define FILTERS  128
#define P_TOTAL  (8 * 256 * 256)   // 524288 pixels

typedef short bf16x8 __attribute__((ext_vector_type(8)));
typedef float f32x4  __attribute__((ext_vector_type(4)));

static __device__ __forceinline__ short f2bf(float f) {
    __hip_bfloat16 h = __float2bfloat16(f);   // RNE
    return *reinterpret_cast<short*>(&h);
}

// ---------------------------------------------------------------------------
// Pre-pack W (fp32 [4][64][128]) into bf16 MFMA A-fragment layout in d_ws.
// frag id = (n*2 + kt)*8 + ft.  Lane l, elem j holds:
//   A[row = f = ft*16 + (l&15)][k = kt*32 + (l>>4)*8 + j]  = W[n][k][f]
// ---------------------------------------------------------------------------
__global__ void prep_w_kernel(const float* __restrict__ W,
                              bf16x8* __restrict__ wp) {
    int t    = blockIdx.x * 256 + threadIdx.x;  // 4096 threads total
    int lane = t & 63;
    int frag = t >> 6;                          // 0..63
    int ft   = frag & 7;
    int kt   = (frag >> 3) & 1;
    int n    = frag >> 4;
    int f    = ft * 16 + (lane & 15);
    int c0   = kt * 32 + (lane >> 4) * 8;
    bf16x8 v;
    #pragma unroll
    for (int j = 0; j < 8; ++j)
        v[j] = f2bf(W[(n * C_IN + c0 + j) * FILTERS + f]);
    wp[(size_t)frag * 64 + lane] = v;
}

// --------------------------- pipeline stages -------------------------------
__device__ __forceinline__ void compute_tile(f32x4 (&acc)[8],
                                             const bf16x8 (&wf)[16],
                                             const bf16x8 (&xbs)[2]) {
    #pragma unroll
    for (int ft = 0; ft < 8; ++ft) acc[ft] = (f32x4){0.f, 0.f, 0.f, 0.f};
    #pragma unroll
    for (int ft = 0; ft < 8; ++ft)
        #pragma unroll
        for (int kt = 0; kt < 2; ++kt)
            acc[ft] = __builtin_amdgcn_mfma_f32_16x16x32_bf16(
                wf[ft * 2 + kt], xbs[kt], acc[ft], 0, 0, 0);
}

// bias + relu + swizzled ds_write into this wave's private buffer.
// D layout: col = lane&15 = pixel, row = lgrp*4 + reg = f within ftile.
__device__ __forceinline__ void stage_tile(f32x4 (*buf)[32],
                                           const f32x4 (&acc)[8],
                                           const f32x4 (&bvn)[8],
                                           int lrow, int lgrp) {
    #pragma unroll
    for (int ft = 0; ft < 8; ++ft) {
        f32x4 v;
        v[0] = fmaxf(acc[ft][0] + bvn[ft][0], 0.f);
        v[1] = fmaxf(acc[ft][1] + bvn[ft][1], 0.f);
        v[2] = fmaxf(acc[ft][2] + bvn[ft][2], 0.f);
        v[3] = fmaxf(acc[ft][3] + bvn[ft][3], 0.f);
        buf[lrow][(ft * 4 + lgrp) ^ (lrow & 7)] = v;
    }
}

// pixel-major read-back -> every global store writes 1KiB fully contiguous.
// A/B vs round 7: PLAIN stores (nt removed) — let L2 absorb/aggregate the
// write stream like the 6.5 TB/s fillBuffer reference does.
__device__ __forceinline__ void drain_tile(const f32x4 (*buf)[32],
                                           f32x4* __restrict__ ob, int lane) {
    #pragma unroll
    for (int i = 0; i < 8; ++i) {
        int px = 2 * i + (lane >> 5);
        int c  = (lane & 31) ^ (px & 7);
        ob[i * 64 + lane] = buf[px][c];
    }
}

// ---------------------------------------------------------------------------
// Main kernel: PERSISTENT waves (round-7 structure). 2048 waves, each owns
// exactly 4 consecutive 64-px tiles — one dispatch sweep, zero generation
// turnovers. Per tile: x -> register B-frags; per n: register-held W frags +
// bias; software-pipelined double-buffered LDS store-transpose (no
// __syncthreads) emitting 1KiB-contiguous stores.
// ---------------------------------------------------------------------------
__global__ __launch_bounds__(128, 2)
void nconv_mfma_kernel(const float* __restrict__ x,
                       const float* __restrict__ bias,
                       const bf16x8* __restrict__ wp,
                       float* __restrict__ out) {
    __shared__ f32x4 lds[2][2][16][32];   // [wave][buf][px][chunk] = 32 KiB

    const int  tid  = threadIdx.x;
    const int  lane = tid & 63;
    const int  widb = tid >> 6;
    const int  wid  = (blockIdx.x * 128 + tid) >> 6;   // 0..2047
    const int  lrow = lane & 15;   // B col -> pixel within sub-tile
    const int  lgrp = lane >> 4;   // k-group / D row-group

    f32x4 (*b0)[32] = lds[widb][0];
    f32x4 (*b1)[32] = lds[widb][1];

    #pragma unroll 1
    for (int t = 0; t < 4; ++t) {
        const long px0 = ((long)wid * 4 + t) * 64;   // consecutive tiles

        // B-frags for 4 sub-tiles of 16 px: x[px][c], 8 contiguous c each.
        bf16x8 xb[4][2];
        #pragma unroll
        for (int s = 0; s < 4; ++s) {
            const float* xp = x + (px0 + s * 16 + lrow) * C_IN + lgrp * 8;
            #pragma unroll
            for (int kt = 0; kt < 2; ++kt) {
                float4 a = *(const float4*)(xp + kt * 32);
                float4 b = *(const float4*)(xp + kt * 32 + 4);
                bf16x8 v;
                v[0] = f2bf(a.x); v[1] = f2bf(a.y); v[2] = f2bf(a.z); v[3] = f2bf(a.w);
                v[4] = f2bf(b.x); v[5] = f2bf(b.y); v[6] = f2bf(b.z); v[7] = f2bf(b.w);
                xb[s][kt] = v;
            }
        }

        #pragma unroll 1   // keep n-loop rolled: wf/bvn lifetime within one n
        for (int n = 0; n < N_CONV; ++n) {
            // W frags for this n: 16 x 16B, register-held, reused by 4 sub-tiles.
            bf16x8 wf[16];
            #pragma unroll
            for (int ft = 0; ft < 8; ++ft)
                #pragma unroll
                for (int kt = 0; kt < 2; ++kt)
                    wf[ft * 2 + kt] = wp[(size_t)((n * 2 + kt) * 8 + ft) * 64 + lane];
            // bias, hoisted so no global-load latency fronts the ds_writes
            f32x4 bvn[8];
            #pragma unroll
            for (int ft = 0; ft < 8; ++ft)
                bvn[ft] = *(const f32x4*)(bias + n * FILTERS + ft * 16 + lgrp * 4);

            f32x4* obase = (f32x4*)out + ((long)n * P_TOTAL + px0) * (FILTERS / 4);
            f32x4 acc[8];

            compute_tile(acc, wf, xb[0]);
            stage_tile(b0, acc, bvn, lrow, lgrp);

            compute_tile(acc, wf, xb[1]);
            stage_tile(b1, acc, bvn, lrow, lgrp);
            drain_tile(b0, obase + 0 * 16 * 32, lane);

            compute_tile(acc, wf, xb[2]);
            stage_tile(b0, acc, bvn, lrow, lgrp);
            drain_tile(b1, obase + 1 * 16 * 32, lane);

            compute_tile(acc, wf, xb[3]);
            stage_tile(b1, acc, bvn, lrow, lgrp);
            drain_tile(b0, obase + 2 * 16 * 32, lane);
            drain_tile(b1, obase + 3 * 16 * 32, lane);
        }
    }
}

extern "C" void kernel_launch(void* const* d_in, const int* in_sizes, int n_in,
                              void* d_out, int out_size, void* d_ws, size_t ws_size,
                              hipStream_t stream) {
    const float* x    = (const float*)d_in[0];
    const float* Wt   = (const float*)d_in[1];
    const float* bias = (const float*)d_in[2];
    float* out        = (float*)d_out;
    bf16x8* wp        = (bf16x8*)d_ws;   // needs 64 KiB scratch

    prep_w_kernel<<<16, 256, 0, stream>>>(Wt, wp);

    // 1024 blocks x 2 waves = 2048 persistent waves; 4 tiles each, no tail.
    nconv_mfma_kernel<<<1024, 128, 0, stream>>>(x, bias, wp, out);
}

// Round 10
// 213.557 us; speedup vs baseline: 1.1913x; 1.1913x over previous
//
#include <hip/hip_runtime.h>
#include <hip/hip_bf16.h>

// Problem constants (match reference setup_inputs)
#define N_CONV   4
#define C_IN     64
#define FILTERS  128
#define P_TOTAL  (8 * 256 * 256)   // 524288 pixels

typedef short bf16x8 __attribute__((ext_vector_type(8)));
typedef float f32x4  __attribute__((ext_vector_type(4)));

static __device__ __forceinline__ short f2bf(float f) {
    __hip_bfloat16 h = __float2bfloat16(f);   // RNE
    return *reinterpret_cast<short*>(&h);
}

// ---------------------------------------------------------------------------
// Pre-pack W (fp32 [4][64][128]) into bf16 MFMA A-fragment layout in d_ws.
// frag id = (n*2 + kt)*8 + ft.  Lane l, elem j holds:
//   A[row = f = ft*16 + (l&15)][k = kt*32 + (l>>4)*8 + j]  = W[n][k][f]
// ---------------------------------------------------------------------------
__global__ void prep_w_kernel(const float* __restrict__ W,
                              bf16x8* __restrict__ wp) {
    int t    = blockIdx.x * 256 + threadIdx.x;  // 4096 threads total
    int lane = t & 63;
    int frag = t >> 6;                          // 0..63
    int ft   = frag & 7;
    int kt   = (frag >> 3) & 1;
    int n    = frag >> 4;
    int f    = ft * 16 + (lane & 15);
    int c0   = kt * 32 + (lane >> 4) * 8;
    bf16x8 v;
    #pragma unroll
    for (int j = 0; j < 8; ++j)
        v[j] = f2bf(W[(n * C_IN + c0 + j) * FILTERS + f]);
    wp[(size_t)frag * 64 + lane] = v;
}

// --------------------------- pipeline stages -------------------------------
__device__ __forceinline__ void compute_tile(f32x4 (&acc)[8],
                                             const bf16x8 (&wf)[16],
                                             const bf16x8 (&xbs)[2]) {
    #pragma unroll
    for (int ft = 0; ft < 8; ++ft) acc[ft] = (f32x4){0.f, 0.f, 0.f, 0.f};
    #pragma unroll
    for (int ft = 0; ft < 8; ++ft)
        #pragma unroll
        for (int kt = 0; kt < 2; ++kt)
            acc[ft] = __builtin_amdgcn_mfma_f32_16x16x32_bf16(
                wf[ft * 2 + kt], xbs[kt], acc[ft], 0, 0, 0);
}

// bias + relu + swizzled ds_write into this wave's private buffer.
// D layout: col = lane&15 = pixel, row = lgrp*4 + reg = f within ftile.
__device__ __forceinline__ void stage_tile(f32x4 (*buf)[32],
                                           const f32x4 (&acc)[8],
                                           const f32x4 (&bvn)[8],
                                           int lrow, int lgrp) {
    #pragma unroll
    for (int ft = 0; ft < 8; ++ft) {
        f32x4 v;
        v[0] = fmaxf(acc[ft][0] + bvn[ft][0], 0.f);
        v[1] = fmaxf(acc[ft][1] + bvn[ft][1], 0.f);
        v[2] = fmaxf(acc[ft][2] + bvn[ft][2], 0.f);
        v[3] = fmaxf(acc[ft][3] + bvn[ft][3], 0.f);
        buf[lrow][(ft * 4 + lgrp) ^ (lrow & 7)] = v;
    }
}

// pixel-major read-back -> every global store writes 1KiB fully contiguous.
// nt stores: R9 A/B proved no-allocate streaming beats write-through-L2 here
// (218 vs 254 us) — keep them.
__device__ __forceinline__ void drain_tile(const f32x4 (*buf)[32],
                                           f32x4* __restrict__ ob, int lane) {
    #pragma unroll
    for (int i = 0; i < 8; ++i) {
        int px = 2 * i + (lane >> 5);
        int c  = (lane & 31) ^ (px & 7);
        __builtin_nontemporal_store(buf[px][c], &ob[i * 64 + lane]);
    }
}

// ---------------------------------------------------------------------------
// Main kernel: PERSISTENT waves (round-7 structure) + CARRIED-DRAIN pipeline.
// 2048 waves, each owns exactly 4 consecutive 64-px tiles. Per (tile,n) unit
// the last-staged buffer is NOT drained inside the unit — it carries as
// `pend` and drains at the START of the next unit, underneath that unit's
// wf/bias loads (and, at tile boundaries, the x loads + f2bf conversions).
// Steady state: one 8-store drain per compute slot, evenly spaced, gapless
// across n and t boundaries. Buffer parity is static: b0,b1,b0,b1 per unit;
// pend always lives in b1.
// ---------------------------------------------------------------------------
__global__ __launch_bounds__(128, 2)
void nconv_mfma_kernel(const float* __restrict__ x,
                       const float* __restrict__ bias,
                       const bf16x8* __restrict__ wp,
                       float* __restrict__ out) {
    __shared__ f32x4 lds[2][2][16][32];   // [wave][buf][px][chunk] = 32 KiB

    const int  tid  = threadIdx.x;
    const int  lane = tid & 63;
    const int  widb = tid >> 6;
    const int  wid  = (blockIdx.x * 128 + tid) >> 6;   // 0..2047
    const int  lrow = lane & 15;   // B col -> pixel within sub-tile
    const int  lgrp = lane >> 4;   // k-group / D row-group

    f32x4 (*b0)[32] = lds[widb][0];
    f32x4 (*b1)[32] = lds[widb][1];

    f32x4* pend = nullptr;   // dst of the staged-but-undrained b1 sub-tile

    #pragma unroll 1
    for (int t = 0; t < 4; ++t) {
        const long px0 = ((long)wid * 4 + t) * 64;   // consecutive tiles

        // B-frags for 4 sub-tiles of 16 px: x[px][c], 8 contiguous c each.
        // (loads issue first; pend drain below overlaps their latency)
        bf16x8 xb[4][2];
        #pragma unroll
        for (int s = 0; s < 4; ++s) {
            const float* xp = x + (px0 + s * 16 + lrow) * C_IN + lgrp * 8;
            #pragma unroll
            for (int kt = 0; kt < 2; ++kt) {
                float4 a = *(const float4*)(xp + kt * 32);
                float4 b = *(const float4*)(xp + kt * 32 + 4);
                bf16x8 v;
                v[0] = f2bf(a.x); v[1] = f2bf(a.y); v[2] = f2bf(a.z); v[3] = f2bf(a.w);
                v[4] = f2bf(b.x); v[5] = f2bf(b.y); v[6] = f2bf(b.z); v[7] = f2bf(b.w);
                xb[s][kt] = v;
            }
        }

        #pragma unroll 1   // keep n-loop rolled: wf/bvn lifetime within one n
        for (int n = 0; n < N_CONV; ++n) {
            // W frags + bias for this n (register-held, reused by 4 sub-tiles).
            bf16x8 wf[16];
            #pragma unroll
            for (int ft = 0; ft < 8; ++ft)
                #pragma unroll
                for (int kt = 0; kt < 2; ++kt)
                    wf[ft * 2 + kt] = wp[(size_t)((n * 2 + kt) * 8 + ft) * 64 + lane];
            f32x4 bvn[8];
            #pragma unroll
            for (int ft = 0; ft < 8; ++ft)
                bvn[ft] = *(const f32x4*)(bias + n * FILTERS + ft * 16 + lgrp * 4);

            // Drain the carried buffer UNDER the wf/bias (and x) load latency.
            if (pend) drain_tile(b1, pend, lane);

            f32x4* obase = (f32x4*)out + ((long)n * P_TOTAL + px0) * (FILTERS / 4);
            f32x4 acc[8];

            compute_tile(acc, wf, xb[0]);
            stage_tile(b0, acc, bvn, lrow, lgrp);

            compute_tile(acc, wf, xb[1]);
            stage_tile(b1, acc, bvn, lrow, lgrp);
            drain_tile(b0, obase + 0 * 16 * 32, lane);

            compute_tile(acc, wf, xb[2]);
            stage_tile(b0, acc, bvn, lrow, lgrp);
            drain_tile(b1, obase + 1 * 16 * 32, lane);

            compute_tile(acc, wf, xb[3]);
            stage_tile(b1, acc, bvn, lrow, lgrp);
            drain_tile(b0, obase + 2 * 16 * 32, lane);

            pend = obase + 3 * 16 * 32;   // b1 holds s3, drained next unit
        }
    }
    if (pend) drain_tile(b1, pend, lane);   // final carried sub-tile
}

extern "C" void kernel_launch(void* const* d_in, const int* in_sizes, int n_in,
                              void* d_out, int out_size, void* d_ws, size_t ws_size,
                              hipStream_t stream) {
    const float* x    = (const float*)d_in[0];
    const float* Wt   = (const float*)d_in[1];
    const float* bias = (const float*)d_in[2];
    float* out        = (float*)d_out;
    bf16x8* wp        = (bf16x8*)d_ws;   // needs 64 KiB scratch

    prep_w_kernel<<<16, 256, 0, stream>>>(Wt, wp);

    // 1024 blocks x 2 waves = 2048 persistent waves; 4 tiles each, no tail.
    nconv_mfma_kernel<<<1024, 128, 0, stream>>>(x, bias, wp, out);
}